// Round 11
// baseline (155.558 us; speedup 1.0000x reference)
//
#include <hip/hip_runtime.h>
#include <cstdint>

typedef short bf16x8 __attribute__((ext_vector_type(8)));
typedef float f32x4 __attribute__((ext_vector_type(4)));
typedef unsigned short u16;
typedef unsigned short u16x8 __attribute__((ext_vector_type(8)));
typedef unsigned int u32;

__device__ inline u16 f2bf(float f) {
  union { float f; unsigned u; } x; x.f = f;
  unsigned u = x.u + 0x7fffu + ((x.u >> 16) & 1u);
  return (u16)(u >> 16);
}
__device__ inline float bf2f(u16 h) {
  union { unsigned u; float f; } x; x.u = ((unsigned)h) << 16;
  return x.f;
}

// ---------------------------------------------------------------------------
// prep: blocks [0,nT): transpose instance_feature -> pf[(b*8+i)][pix][c] bf16
//       blocks [nT, nT+576): weight transpose wtr[s][tap][u][c] bf16
//       blocks [nT+576, ...): bgf fp32 -> bgp bf16 packed
// ---------------------------------------------------------------------------
__global__ __launch_bounds__(256) void prep_kernel(
    const float* __restrict__ inst, u16* __restrict__ pf,
    const float* __restrict__ w0, const float* __restrict__ w1,
    const float* __restrict__ w2, const float* __restrict__ w3,
    u16* __restrict__ wtr,
    const float* __restrict__ bgf, u16* __restrict__ bgp, int nT)
{
  if ((int)blockIdx.x < nT) {
    const int lane = threadIdx.x & 63;
    const int wvid = blockIdx.x * 4 + (threadIdx.x >> 6);  // 0..16383
    const int b = wvid >> 12;
    const int pix = wvid & 4095;
    const float* s = inst + ((size_t)(b * 4096 + pix)) * 512 + lane * 8;
    float4 v0 = *(const float4*)s;
    float4 v1 = *(const float4*)(s + 4);
    float vals[8] = {v0.x, v0.y, v0.z, v0.w, v1.x, v1.y, v1.z, v1.w};
    #pragma unroll
    for (int i = 0; i < 8; i++)
      pf[(((size_t)(b * 8 + i)) * 4096 + pix) * 64 + lane] = f2bf(vals[i]);
  } else if ((int)blockIdx.x < nT + 576) {
    int id = (blockIdx.x - nT) * 256 + threadIdx.x;
    if (id >= 147456) return;
    int s = id / 36864;
    int r = id - s * 36864;
    int tap = r >> 12;
    int rc = r & 4095;
    int c = rc >> 6, u = rc & 63;
    const float* Ws = (s == 0) ? w0 : (s == 1) ? w1 : (s == 2) ? w2 : w3;
    wtr[(size_t)s * 36864 + ((size_t)tap * 64 + u) * 64 + c] =
        f2bf(Ws[((size_t)tap * 64 + c) * 64 + u]);
  } else {
    size_t id = (size_t)(blockIdx.x - nT - 576) * 256 + threadIdx.x;
    const float* s = bgf + id * 8;
    float4 v0 = *(const float4*)s;
    float4 v1 = *(const float4*)(s + 4);
    u16x8 o;
    o[0] = f2bf(v0.x); o[1] = f2bf(v0.y); o[2] = f2bf(v0.z); o[3] = f2bf(v0.w);
    o[4] = f2bf(v1.x); o[5] = f2bf(v1.y); o[6] = f2bf(v1.z); o[7] = f2bf(v1.w);
    *(u16x8*)(bgp + id * 8) = o;
  }
}

// ---------------------------------------------------------------------------
// conv 3x3 SAME, 64->64, bias+relu, bf16 MFMA implicit GEMM.
// 32x16 pixel tile, 4 waves, 128 px/wave (mf=8): 12 ds_reads per 32 MFMA.
// A: 34x18x64 halo in LDS (XOR-swizzled). B: ping-pong 2x8KB in LDS,
// register-prefetched, ONE barrier per tap (8 total).
// SRC: 0 = fp32 packed [img][pix][64], 1 = bf16 packed, 2 = fp32 native inst.
// ---------------------------------------------------------------------------
#define BOFF0 78336   // 612 hpix * 128 B
template<int SRC>
__device__ __forceinline__ void conv_body(
    char* smem, const void* __restrict__ inv, const u16* __restrict__ wtr,
    const float* __restrict__ bias, u16* __restrict__ out,
    int H, int W, int bid)
{
  const int tilesX = W >> 4;
  const int tilesPerImg = (H >> 5) * tilesX;
  const int img = bid / tilesPerImg;
  const int tile = bid - img * tilesPerImg;
  const int ty = (tile / tilesX) << 5;
  const int tx = (tile % tilesX) << 4;
  const int tid = threadIdx.x;

  // ---- stage A halo (34x18 pixels x 64 c) as swizzled bf16
  for (int idx = tid; idx < 4896; idx += 256) {
    int hpix = idx >> 3;
    int c0 = (idx & 7) << 3;
    int hy = hpix / 18, hx = hpix - hy * 18;
    int gy = ty + hy - 1, gx = tx + hx - 1;
    u16x8 v = {0, 0, 0, 0, 0, 0, 0, 0};
    if (gy >= 0 && gy < H && gx >= 0 && gx < W) {
      if (SRC == 0) {
        const float* s = (const float*)inv + ((size_t)img * H * W + (size_t)gy * W + gx) * 64 + c0;
        #pragma unroll
        for (int j = 0; j < 8; j++) v[j] = f2bf(s[j]);
      } else if (SRC == 1) {
        const u16* s = (const u16*)inv + ((size_t)img * H * W + (size_t)gy * W + gx) * 64 + c0;
        v = *(const u16x8*)s;
      } else {
        int bb = img >> 3, ii = img & 7;
        const float* s = (const float*)inv + ((((size_t)bb * 64 + gy) * 64 + gx) * 64 + c0) * 8 + ii;
        #pragma unroll
        for (int j = 0; j < 8; j++) v[j] = f2bf(s[j * 8]);
      }
    }
    int byte = (hpix * 128 + c0 * 2) ^ ((hpix & 7) << 4);
    *(u16x8*)(smem + byte) = v;
  }

  const int lane = tid & 63;
  const int wv = tid >> 6;
  const int lrow = lane & 15;
  const int kg = lane >> 4;

  // B chunk ids (2 x 16B per tap per thread); relative swizzled offsets
  const int ch0 = tid, ch1 = tid + 256;
  const int bu0 = ch0 >> 3, bc0 = (ch0 & 7) << 3;
  const int bu1 = ch1 >> 3, bc1 = (ch1 & 7) << 3;
  const int brel0 = (bu0 * 128 + bc0 * 2) ^ ((bu0 & 7) << 4);
  const int brel1 = (bu1 * 128 + bc1 * 2) ^ ((bu1 & 7) << 4);

  // stage B tap 0 -> buf 0
  {
    u16x8 n0 = *(const u16x8*)(wtr + (size_t)bu0 * 64 + bc0);
    u16x8 n1 = *(const u16x8*)(wtr + (size_t)bu1 * 64 + bc1);
    *(u16x8*)(smem + BOFF0 + brel0) = n0;
    *(u16x8*)(smem + BOFF0 + brel1) = n1;
  }
  __syncthreads();

  int pyv[8], pxv[8];
  #pragma unroll
  for (int mf = 0; mf < 8; mf++) {
    int p = wv * 128 + mf * 16 + lrow;
    pyv[mf] = p >> 4; pxv[mf] = p & 15;
  }

  f32x4 acc[8][4];
  #pragma unroll
  for (int a = 0; a < 8; a++)
    #pragma unroll
    for (int b = 0; b < 4; b++) { f32x4 z = {0.f, 0.f, 0.f, 0.f}; acc[a][b] = z; }

  for (int tap = 0; tap < 9; tap++) {
    u16x8 n0, n1;
    if (tap < 8) {
      n0 = *(const u16x8*)(wtr + (size_t)((tap + 1) * 64 + bu0) * 64 + bc0);
      n1 = *(const u16x8*)(wtr + (size_t)((tap + 1) * 64 + bu1) * 64 + bc1);
    }
    const int ky = tap / 3, kx = tap - ky * 3;
    const int bbase = BOFF0 + ((tap & 1) << 13);
    #pragma unroll
    for (int ks = 0; ks < 2; ks++) {
      bf16x8 Bf[4];
      #pragma unroll
      for (int nf = 0; nf < 4; nf++) {
        int u = nf * 16 + lrow;
        int byte = bbase + ((u * 128 + ks * 64 + kg * 16) ^ ((u & 7) << 4));
        Bf[nf] = *(const bf16x8*)(smem + byte);
      }
      #pragma unroll
      for (int mf = 0; mf < 8; mf++) {
        int hpix = (pyv[mf] + ky) * 18 + pxv[mf] + kx;
        int byte = (hpix * 128 + ks * 64 + kg * 16) ^ ((hpix & 7) << 4);
        bf16x8 Af = *(const bf16x8*)(smem + byte);
        #pragma unroll
        for (int nf = 0; nf < 4; nf++)
          acc[mf][nf] = __builtin_amdgcn_mfma_f32_16x16x32_bf16(Af, Bf[nf], acc[mf][nf], 0, 0, 0);
      }
    }
    if (tap < 8) {  // write NEXT tap's B into the OTHER buffer, one barrier
      const int nb = BOFF0 + (((tap + 1) & 1) << 13);
      *(u16x8*)(smem + nb + brel0) = n0;
      *(u16x8*)(smem + nb + brel1) = n1;
      __syncthreads();
    }
  }

  float bv[4];
  #pragma unroll
  for (int nf = 0; nf < 4; nf++) bv[nf] = bias[nf * 16 + lrow];

  const size_t obase = (size_t)img * H * W;
  #pragma unroll
  for (int mf = 0; mf < 8; mf++) {
    #pragma unroll
    for (int j = 0; j < 4; j++) {
      int p = wv * 128 + mf * 16 + kg * 4 + j;
      int oy = ty + (p >> 4), ox = tx + (p & 15);
      u16* op = out + (obase + (size_t)oy * W + ox) * 64 + lrow;
      #pragma unroll
      for (int nf = 0; nf < 4; nf++)
        op[nf * 16] = f2bf(fmaxf(acc[mf][nf][j] + bv[nf], 0.0f));
    }
  }
}

// dual dispatcher: blocks [0,split) = set 1, [split, n) = set 2.
template<int S1, int S2>
__global__ __launch_bounds__(256, 1) void conv_dual(
    const void* in1, const u16* w1, const float* b1, u16* o1, int H1, int W1, int split,
    const void* in2, const u16* w2, const float* b2, u16* o2, int H2, int W2)
{
  __shared__ __align__(16) char smem[94720];  // A 78336 + B 2x8192
  if ((int)blockIdx.x < split)
    conv_body<S1>(smem, in1, w1, b1, o1, H1, W1, blockIdx.x);
  else
    conv_body<S2>(smem, in2, w2, b2, o2, H2, W2, blockIdx.x - split);
}

// ---------------------------------------------------------------------------
// conv 3x3 SAME, 64->1, bias+relu. Tiled: 16x16 px/block, thread=pixel.
// ---------------------------------------------------------------------------
__device__ __forceinline__ void conv3_body(
    char* smem, const u16* __restrict__ in, const float* __restrict__ W3,
    const float* __restrict__ b3, float* __restrict__ out, int H, int W, int bid)
{
  float* wlds = (float*)(smem + 41472);
  const int tilesX = W >> 4;
  const int tilesPerImg = (H >> 4) * tilesX;
  const int img = bid / tilesPerImg;
  const int tile = bid - img * tilesPerImg;
  const int ty = (tile / tilesX) << 4;
  const int tx = (tile % tilesX) << 4;
  const int tid = threadIdx.x;

  for (int idx = tid; idx < 2592; idx += 256) {
    int hpix = idx >> 3;
    int c0 = (idx & 7) << 3;
    int hy = hpix / 18, hx = hpix - hy * 18;
    int gy = ty + hy - 1, gx = tx + hx - 1;
    u16x8 v = {0, 0, 0, 0, 0, 0, 0, 0};
    if (gy >= 0 && gy < H && gx >= 0 && gx < W)
      v = *(const u16x8*)(in + ((size_t)img * H * W + (size_t)gy * W + gx) * 64 + c0);
    int byte = (hpix * 128 + c0 * 2) ^ ((hpix & 7) << 4);
    *(u16x8*)(smem + byte) = v;
  }
  for (int idx = tid; idx < 576; idx += 256) wlds[idx] = W3[idx];
  __syncthreads();

  const int py = tid >> 4, px = tid & 15;
  float acc = 0.0f;
  #pragma unroll
  for (int ky = 0; ky < 3; ky++) {
    #pragma unroll
    for (int kx = 0; kx < 3; kx++) {
      const int hpix = (py + ky) * 18 + (px + kx);
      const float* wp = wlds + (ky * 3 + kx) * 64;
      #pragma unroll
      for (int cg = 0; cg < 8; cg++) {
        int byte = (hpix * 128 + cg * 16) ^ ((hpix & 7) << 4);
        u16x8 v = *(const u16x8*)(smem + byte);
        #pragma unroll
        for (int j = 0; j < 8; j++)
          acc = fmaf(bf2f(v[j]), wp[cg * 8 + j], acc);
      }
    }
  }
  out[(size_t)img * H * W + (size_t)(ty + py) * W + (tx + px)] =
      fmaxf(acc + b3[0], 0.0f);
}

__global__ __launch_bounds__(256) void conv3_dual(
    const u16* in1, const float* W31, const float* b31, float* o1, int H1, int W1, int split,
    const u16* in2, const float* W32, const float* b32, float* o2, int H2, int W2)
{
  __shared__ __align__(16) char smem[43776];
  if ((int)blockIdx.x < split)
    conv3_body(smem, in1, W31, b31, o1, H1, W1, blockIdx.x);
  else
    conv3_body(smem, in2, W32, b32, o2, H2, W2, blockIdx.x - split);
}

// ---------------------------------------------------------------------------
// precompute per-pixel softmax params: thread = pixel (65536 threads).
// Packs per-(pixel,instance): float4(wi, fy, fx, bits(yx)).
// ---------------------------------------------------------------------------
__global__ __launch_bounds__(256) void precompute_params(
    const float* __restrict__ bbox, const float* __restrict__ mask,
    const float* __restrict__ iw, const float* __restrict__ bgw,
    float* __restrict__ pp_wbg, float4* __restrict__ pp_s)
{
  const int gpix = blockIdx.x * 256 + threadIdx.x;  // 0..65535
  const int b = gpix >> 14;
  const int p = gpix & 16383;
  const int Y = p >> 7, X = p & 127;

  float msy = ((float)Y + 0.5f) * 0.4375f - 0.5f;
  msy = fminf(fmaxf(msy, 0.0f), 55.0f);
  int my0 = (int)floorf(msy); int my1 = min(my0 + 1, 55); float fmy = msy - (float)my0;
  float msx = ((float)X + 0.5f) * 0.4375f - 0.5f;
  msx = fminf(fmaxf(msx, 0.0f), 55.0f);
  int mx0 = (int)floorf(msx); int mx1 = min(mx0 + 1, 55); float fmx = msx - (float)mx0;

  const float ewbg = expf(bgw[gpix]);
  float denom = ewbg;
  float wi_l[8];
  u32 yx_l[8];
  float fy_l[8], fx_l[8];

  #pragma unroll
  for (int i = 0; i < 8; i++) {
    float by1 = bbox[(b * 4 + 0) * 8 + i];
    float by2 = bbox[(b * 4 + 1) * 8 + i];
    float bx1 = bbox[(b * 4 + 2) * 8 + i];
    float bx2 = bbox[(b * 4 + 3) * 8 + i];
    int ysz = max((int)(128.0f * (by2 - by1)), 1);
    int xsz = max((int)(128.0f * (bx2 - bx1)), 1);
    int yfr = (int)(128.0f * by1);
    int xfr = (int)(128.0f * bx1);
    int ly = Y - yfr, lx = X - xfr;
    bool valid = (ly >= 0) && (ly < ysz) && (lx >= 0) && (lx < xsz);
    float rwv = 0.0f;
    int y0 = 0, y1i = 0, x0 = 0, x1i = 0;
    float fy = 0.0f, fx = 0.0f;
    if (valid) {
      float sy = ((float)ly + 0.5f) * (64.0f / (float)ysz) - 0.5f;
      sy = fminf(fmaxf(sy, 0.0f), 63.0f);
      y0 = (int)floorf(sy); y1i = min(y0 + 1, 63); fy = sy - (float)y0;
      float sx = ((float)lx + 0.5f) * (64.0f / (float)xsz) - 0.5f;
      sx = fminf(fmaxf(sx, 0.0f), 63.0f);
      x0 = (int)floorf(sx); x1i = min(x0 + 1, 63); fx = sx - (float)x0;
      const float* iwp = iw + ((size_t)(b * 8 + i)) * 4096;
      float v00 = iwp[y0 * 64 + x0],  v01 = iwp[y0 * 64 + x1i];
      float v10 = iwp[y1i * 64 + x0], v11 = iwp[y1i * 64 + x1i];
      rwv = v00 * (1.f - fy) * (1.f - fx) + v01 * (1.f - fy) * fx
          + v10 * fy * (1.f - fx)         + v11 * fy * fx;
    }
    const float* mp = mask + (size_t)b * 56 * 56 * 8 + i;
    float m00 = mp[(my0 * 56 + mx0) * 8], m01 = mp[(my0 * 56 + mx1) * 8];
    float m10 = mp[(my1 * 56 + mx0) * 8], m11 = mp[(my1 * 56 + mx1) * 8];
    float rm = m00 * (1.f - fmy) * (1.f - fmx) + m01 * (1.f - fmy) * fmx
             + m10 * fmy * (1.f - fmx)         + m11 * fmy * fmx;
    float ew = expf(rwv) * rm;
    denom += ew;
    wi_l[i] = valid ? ew : 0.0f;
    yx_l[i] = (u32)y0 | ((u32)x0 << 8) | ((u32)y1i << 16) | ((u32)x1i << 24);
    fy_l[i] = fy; fx_l[i] = fx;
  }

  const float invd = 1.0f / denom;
  pp_wbg[gpix] = ewbg * invd;
  float4* qs = pp_s + ((size_t)gpix << 3);
  #pragma unroll
  for (int i = 0; i < 8; i++) {
    float4 q;
    q.x = wi_l[i] * invd;
    q.y = fy_l[i];
    q.z = fx_l[i];
    q.w = __uint_as_float(yx_l[i]);
    qs[i] = q;
  }
}

// ---------------------------------------------------------------------------
// final blend: wave per pixel (max TLP), lane = channel. Packed float4 params,
// all 8 q-loads hoisted (unguarded) for VMEM ILP; gathers stay execz-guarded.
// ---------------------------------------------------------------------------
__global__ __launch_bounds__(256) void final_blend(
    const u16* __restrict__ pf, const float* __restrict__ bgf,
    const float* __restrict__ pp_wbg, const float4* __restrict__ pp_s,
    float* __restrict__ out)
{
  const int lane = threadIdx.x & 63;
  const int gpix = blockIdx.x * 4 + (threadIdx.x >> 6);  // grid = 16384 blocks
  const int b = gpix >> 14;

  float4 q[8];
  const float4* qs = pp_s + ((size_t)gpix << 3);
  #pragma unroll
  for (int i = 0; i < 8; i++) q[i] = qs[i];

  float accv = pp_wbg[gpix] * bgf[(size_t)gpix * 64 + lane];
  const u16* pfb = pf + (size_t)b * 8 * 262144;
  #pragma unroll
  for (int i = 0; i < 8; i++) {
    if (q[i].x != 0.0f) {   // wave-uniform -> execz skip
      u32 yx = __float_as_uint(q[i].w);
      int y0 = yx & 255, x0 = (yx >> 8) & 255;
      int y1i = (yx >> 16) & 255, x1i = (yx >> 24) & 255;
      const u16* fp = pfb + (size_t)i * 262144;
      float g00 = bf2f(fp[((size_t)(y0 * 64 + x0)) * 64 + lane]);
      float g01 = bf2f(fp[((size_t)(y0 * 64 + x1i)) * 64 + lane]);
      float g10 = bf2f(fp[((size_t)(y1i * 64 + x0)) * 64 + lane]);
      float g11 = bf2f(fp[((size_t)(y1i * 64 + x1i)) * 64 + lane]);
      float s = g00 * (1.f - q[i].y) * (1.f - q[i].z) + g01 * (1.f - q[i].y) * q[i].z
              + g10 * q[i].y * (1.f - q[i].z)         + g11 * q[i].y * q[i].z;
      accv = fmaf(q[i].x, s, accv);
    }
  }
  out[(size_t)gpix * 64 + lane] = accv;
}

// ---------------------------------------------------------------------------
// fallback full final (no packed features). Wave per pixel, lane = c.
// ---------------------------------------------------------------------------
__global__ __launch_bounds__(256) void final_kernel_fb(
    const float* __restrict__ inst, const float* __restrict__ bgf,
    const float* __restrict__ bbox, const float* __restrict__ mask,
    const float* __restrict__ iw, const float* __restrict__ bgw,
    float* __restrict__ out)
{
  const int lane = threadIdx.x & 63;
  const int wvid = blockIdx.x * 4 + (threadIdx.x >> 6);
  const int nw = gridDim.x * 4;
  for (int pix = wvid; pix < 4 * 128 * 128; pix += nw) {
    const int b = pix >> 14;
    const int p = pix & 16383;
    const int Y = p >> 7, X = p & 127;

    float msy = ((float)Y + 0.5f) * 0.4375f - 0.5f;
    msy = fminf(fmaxf(msy, 0.0f), 55.0f);
    int my0 = (int)floorf(msy); int my1 = min(my0 + 1, 55); float fmy = msy - (float)my0;
    float msx = ((float)X + 0.5f) * 0.4375f - 0.5f;
    msx = fminf(fmaxf(msx, 0.0f), 55.0f);
    int mx0 = (int)floorf(msx); int mx1 = min(mx0 + 1, 55); float fmx = msx - (float)mx0;

    const float ewbg = expf(bgw[(size_t)b * 16384 + p]);
    float denom = ewbg;
    float acc = 0.0f;

    for (int i = 0; i < 8; i++) {
      float by1 = bbox[(b * 4 + 0) * 8 + i];
      float by2 = bbox[(b * 4 + 1) * 8 + i];
      float bx1 = bbox[(b * 4 + 2) * 8 + i];
      float bx2 = bbox[(b * 4 + 3) * 8 + i];
      int ysz = max((int)(128.0f * (by2 - by1)), 1);
      int xsz = max((int)(128.0f * (bx2 - bx1)), 1);
      int yfr = (int)(128.0f * by1);
      int xfr = (int)(128.0f * bx1);
      int ly = Y - yfr, lx = X - xfr;
      bool valid = (ly >= 0) && (ly < ysz) && (lx >= 0) && (lx < xsz);
      float rwv = 0.0f;
      int y0 = 0, y1i = 0, x0 = 0, x1i = 0;
      float fy = 0.0f, fx = 0.0f;
      if (valid) {
        float sy = ((float)ly + 0.5f) * (64.0f / (float)ysz) - 0.5f;
        sy = fminf(fmaxf(sy, 0.0f), 63.0f);
        y0 = (int)floorf(sy); y1i = min(y0 + 1, 63); fy = sy - (float)y0;
        float sx = ((float)lx + 0.5f) * (64.0f / (float)xsz) - 0.5f;
        sx = fminf(fmaxf(sx, 0.0f), 63.0f);
        x0 = (int)floorf(sx); x1i = min(x0 + 1, 63); fx = sx - (float)x0;
        const float* iwp = iw + ((size_t)(b * 8 + i)) * 4096;
        float v00 = iwp[y0 * 64 + x0],  v01 = iwp[y0 * 64 + x1i];
        float v10 = iwp[y1i * 64 + x0], v11 = iwp[y1i * 64 + x1i];
        rwv = v00 * (1.f - fy) * (1.f - fx) + v01 * (1.f - fy) * fx
            + v10 * fy * (1.f - fx)         + v11 * fy * fx;
      }
      const float* mp = mask + (size_t)b * 56 * 56 * 8 + i;
      float m00 = mp[(my0 * 56 + mx0) * 8], m01 = mp[(my0 * 56 + mx1) * 8];
      float m10 = mp[(my1 * 56 + mx0) * 8], m11 = mp[(my1 * 56 + mx1) * 8];
      float rm = m00 * (1.f - fmy) * (1.f - fmx) + m01 * (1.f - fmy) * fmx
               + m10 * fmy * (1.f - fmx)         + m11 * fmy * fmx;
      float ew = expf(rwv) * rm;
      denom += ew;
      if (valid) {
        const float* fp = inst + (size_t)b * 2097152 + i;
        float g00 = fp[(((size_t)y0 * 64 + x0) * 64 + lane) * 8];
        float g01 = fp[(((size_t)y0 * 64 + x1i) * 64 + lane) * 8];
        float g10 = fp[(((size_t)y1i * 64 + x0) * 64 + lane) * 8];
        float g11 = fp[(((size_t)y1i * 64 + x1i) * 64 + lane) * 8];
        float s = g00 * (1.f - fy) * (1.f - fx) + g01 * (1.f - fy) * fx
                + g10 * fy * (1.f - fx)         + g11 * fy * fx;
        acc += ew * s;
      }
    }
    const float bgv = bgf[((size_t)b * 16384 + p) * 64 + lane];
    out[((size_t)b * 16384 + p) * 64 + lane] = (ewbg * bgv + acc) / denom;
  }
}

// ---------------------------------------------------------------------------
extern "C" void kernel_launch(void* const* d_in, const int* in_sizes, int n_in,
                              void* d_out, int out_size, void* d_ws, size_t ws_size,
                              hipStream_t stream) {
  const float* inst = (const float*)d_in[0];
  const float* bgf  = (const float*)d_in[1];
  const float* bbox = (const float*)d_in[2];
  const float* mask = (const float*)d_in[3];
  const float* iW1 = (const float*)d_in[4];  const float* ib1 = (const float*)d_in[5];
  const float* iW2 = (const float*)d_in[6];  const float* ib2 = (const float*)d_in[7];
  const float* iW3 = (const float*)d_in[8];  const float* ib3 = (const float*)d_in[9];
  const float* bW1 = (const float*)d_in[10]; const float* bb1 = (const float*)d_in[11];
  const float* bW2 = (const float*)d_in[12]; const float* bb2 = (const float*)d_in[13];
  const float* bW3 = (const float*)d_in[14]; const float* bb3 = (const float*)d_in[15];

  char* ws = (char*)d_ws;
  u16*   wtr  = (u16*)ws;                         // 294,912 B
  u16*   AbI  = (u16*)(ws + 294912);              // 16,777,216 B (inst L1 out)
  u16*   AbB  = (u16*)(ws + 17072128);            //  8,388,608 B (bg L1 out)
  u16*   BbI  = (u16*)(ws + 25460736);            // 16,777,216 B (inst L2 out)
  u16*   BbB  = (u16*)(ws + 42237952);            //  8,388,608 B (bg L2 out)
  float* iw   = (float*)(ws + 50626560);          //    524,288 B
  float* bgw  = (float*)(ws + 51150848);          //    262,144 B
  u16*   pf   = (u16*)(ws + 51412992);            // 16,777,216 B (bf16 packed feats)
  u16*   bgp  = (u16*)(ws + 68190208);            //  8,388,608 B (bf16 bg, dedicated)
  const bool usePf = ws_size >= (size_t)76578816;
  float* outp = (float*)d_out;

  // softmax params overlap the (dead after conv L2) AbI region:
  // wbg 256KB + structs 8.4MB = 8.7MB < 16.7MB
  float*  pp_wbg = (float*) (ws + 294912);
  float4* pp_s   = (float4*)(ws + 294912 + 262144);

  if (usePf) {
    // 4096 transpose + 576 wtrans + 2048 bg-convert
    prep_kernel<<<6720, 256, 0, stream>>>(inst, pf, iW1, iW2, bW1, bW2, wtr,
                                          bgf, bgp, 4096);
    // 32x16 tiles: inst 32 imgs x 8 = 256 blocks, bg 4 x 32 = 128 -> 384
    conv_dual<1, 1><<<384, 256, 0, stream>>>(
        pf,  wtr,             ib1, AbI, 64, 64, 256,
        bgp, wtr + 2 * 36864, bb1, AbB, 128, 128);
    conv_dual<1, 1><<<384, 256, 0, stream>>>(
        AbI, wtr + 36864,     ib2, BbI, 64, 64, 256,
        AbB, wtr + 3 * 36864, bb2, BbB, 128, 128);
    conv3_dual<<<768, 256, 0, stream>>>(
        BbI, iW3, ib3, iw, 64, 64, 512,
        BbB, bW3, bb3, bgw, 128, 128);
    precompute_params<<<256, 256, 0, stream>>>(bbox, mask, iw, bgw, pp_wbg, pp_s);
    final_blend<<<16384, 256, 0, stream>>>(pf, bgf, pp_wbg, pp_s, outp);
  } else {
    prep_kernel<<<576, 256, 0, stream>>>(inst, pf, iW1, iW2, bW1, bW2, wtr,
                                         bgf, bgp, 0);   // wtrans only
    conv_dual<2, 0><<<384, 256, 0, stream>>>(
        inst, wtr,            ib1, AbI, 64, 64, 256,
        bgf, wtr + 2 * 36864, bb1, AbB, 128, 128);
    conv_dual<1, 1><<<384, 256, 0, stream>>>(
        AbI, wtr + 36864,     ib2, BbI, 64, 64, 256,
        AbB, wtr + 3 * 36864, bb2, BbB, 128, 128);
    conv3_dual<<<768, 256, 0, stream>>>(
        BbI, iW3, ib3, iw, 64, 64, 512,
        BbB, bW3, bb3, bgw, 128, 128);
    final_kernel_fb<<<2048, 256, 0, stream>>>(inst, bgf, bbox, mask, iw, bgw, outp);
  }
}

// Round 12
// 113.308 us; speedup vs baseline: 1.3729x; 1.3729x over previous
//
#include <hip/hip_runtime.h>
#include <cstdint>

typedef short bf16x8 __attribute__((ext_vector_type(8)));
typedef float f32x4 __attribute__((ext_vector_type(4)));
typedef unsigned short u16;
typedef unsigned short u16x8 __attribute__((ext_vector_type(8)));
typedef unsigned int u32;

__device__ inline u16 f2bf(float f) {
  union { float f; unsigned u; } x; x.f = f;
  unsigned u = x.u + 0x7fffu + ((x.u >> 16) & 1u);
  return (u16)(u >> 16);
}
__device__ inline float bf2f(u16 h) {
  union { unsigned u; float f; } x; x.u = ((unsigned)h) << 16;
  return x.f;
}

// ---------------------------------------------------------------------------
// prep: blocks [0,nT): transpose instance_feature -> pf[(b*8+i)][pix][c] bf16
//       blocks [nT, nT+576): weight transpose wtr[s][tap][u][c] bf16
//       blocks [nT+576, ...): bgf fp32 -> bgp bf16 packed
// ---------------------------------------------------------------------------
__global__ __launch_bounds__(256) void prep_kernel(
    const float* __restrict__ inst, u16* __restrict__ pf,
    const float* __restrict__ w0, const float* __restrict__ w1,
    const float* __restrict__ w2, const float* __restrict__ w3,
    u16* __restrict__ wtr,
    const float* __restrict__ bgf, u16* __restrict__ bgp, int nT)
{
  if ((int)blockIdx.x < nT) {
    const int lane = threadIdx.x & 63;
    const int wvid = blockIdx.x * 4 + (threadIdx.x >> 6);  // 0..16383
    const int b = wvid >> 12;
    const int pix = wvid & 4095;
    const float* s = inst + ((size_t)(b * 4096 + pix)) * 512 + lane * 8;
    float4 v0 = *(const float4*)s;
    float4 v1 = *(const float4*)(s + 4);
    float vals[8] = {v0.x, v0.y, v0.z, v0.w, v1.x, v1.y, v1.z, v1.w};
    #pragma unroll
    for (int i = 0; i < 8; i++)
      pf[(((size_t)(b * 8 + i)) * 4096 + pix) * 64 + lane] = f2bf(vals[i]);
  } else if ((int)blockIdx.x < nT + 576) {
    int id = (blockIdx.x - nT) * 256 + threadIdx.x;
    if (id >= 147456) return;
    int s = id / 36864;
    int r = id - s * 36864;
    int tap = r >> 12;
    int rc = r & 4095;
    int c = rc >> 6, u = rc & 63;
    const float* Ws = (s == 0) ? w0 : (s == 1) ? w1 : (s == 2) ? w2 : w3;
    wtr[(size_t)s * 36864 + ((size_t)tap * 64 + u) * 64 + c] =
        f2bf(Ws[((size_t)tap * 64 + c) * 64 + u]);
  } else {
    size_t id = (size_t)(blockIdx.x - nT - 576) * 256 + threadIdx.x;
    const float* s = bgf + id * 8;
    float4 v0 = *(const float4*)s;
    float4 v1 = *(const float4*)(s + 4);
    u16x8 o;
    o[0] = f2bf(v0.x); o[1] = f2bf(v0.y); o[2] = f2bf(v0.z); o[3] = f2bf(v0.w);
    o[4] = f2bf(v1.x); o[5] = f2bf(v1.y); o[6] = f2bf(v1.z); o[7] = f2bf(v1.w);
    *(u16x8*)(bgp + id * 8) = o;
  }
}

// ---------------------------------------------------------------------------
// conv 3x3 SAME, 64->64, bias+relu, bf16 MFMA implicit GEMM (round-10 proven).
// 16x16 tile, 4 waves, A halo + per-tap B staged in LDS, reg-prefetch B.
// ---------------------------------------------------------------------------
#define BOFF 41472
template<int SRC>
__device__ __forceinline__ void conv_body(
    char* smem, const void* __restrict__ inv, const u16* __restrict__ wtr,
    const float* __restrict__ bias, u16* __restrict__ out,
    int H, int W, int bid)
{
  const int tilesX = W >> 4;
  const int tilesPerImg = (H >> 4) * tilesX;
  const int img = bid / tilesPerImg;
  const int tile = bid - img * tilesPerImg;
  const int ty = (tile / tilesX) << 4;
  const int tx = (tile % tilesX) << 4;
  const int tid = threadIdx.x;

  for (int idx = tid; idx < 2592; idx += 256) {
    int hpix = idx >> 3;
    int c0 = (idx & 7) << 3;
    int hy = hpix / 18, hx = hpix - hy * 18;
    int gy = ty + hy - 1, gx = tx + hx - 1;
    u16x8 v = {0, 0, 0, 0, 0, 0, 0, 0};
    if (gy >= 0 && gy < H && gx >= 0 && gx < W) {
      if (SRC == 0) {
        const float* s = (const float*)inv + ((size_t)img * H * W + (size_t)gy * W + gx) * 64 + c0;
        #pragma unroll
        for (int j = 0; j < 8; j++) v[j] = f2bf(s[j]);
      } else if (SRC == 1) {
        const u16* s = (const u16*)inv + ((size_t)img * H * W + (size_t)gy * W + gx) * 64 + c0;
        v = *(const u16x8*)s;
      } else {
        int bb = img >> 3, ii = img & 7;
        const float* s = (const float*)inv + ((((size_t)bb * 64 + gy) * 64 + gx) * 64 + c0) * 8 + ii;
        #pragma unroll
        for (int j = 0; j < 8; j++) v[j] = f2bf(s[j * 8]);
      }
    }
    int byte = (hpix * 128 + c0 * 2) ^ ((hpix & 7) << 4);
    *(u16x8*)(smem + byte) = v;
  }

  const int lane = tid & 63;
  const int wv = tid >> 6;
  const int lrow = lane & 15;
  const int kg = lane >> 4;

  const int ch0 = tid, ch1 = tid + 256;
  const int bu0 = ch0 >> 3, bc0 = (ch0 & 7) << 3;
  const int bu1 = ch1 >> 3, bc1 = (ch1 & 7) << 3;
  const int bdst0 = BOFF + ((bu0 * 128 + bc0 * 2) ^ ((bu0 & 7) << 4));
  const int bdst1 = BOFF + ((bu1 * 128 + bc1 * 2) ^ ((bu1 & 7) << 4));

  {
    u16x8 n0 = *(const u16x8*)(wtr + (size_t)(0 * 64 + bu0) * 64 + bc0);
    u16x8 n1 = *(const u16x8*)(wtr + (size_t)(0 * 64 + bu1) * 64 + bc1);
    *(u16x8*)(smem + bdst0) = n0;
    *(u16x8*)(smem + bdst1) = n1;
  }
  __syncthreads();

  int pyv[4], pxv[4];
  #pragma unroll
  for (int mf = 0; mf < 4; mf++) {
    int p = wv * 64 + mf * 16 + lrow;
    pyv[mf] = p >> 4; pxv[mf] = p & 15;
  }

  f32x4 acc[4][4];
  #pragma unroll
  for (int a = 0; a < 4; a++)
    #pragma unroll
    for (int b = 0; b < 4; b++) { f32x4 z = {0.f, 0.f, 0.f, 0.f}; acc[a][b] = z; }

  for (int tap = 0; tap < 9; tap++) {
    u16x8 n0, n1;
    if (tap < 8) {
      n0 = *(const u16x8*)(wtr + (size_t)((tap + 1) * 64 + bu0) * 64 + bc0);
      n1 = *(const u16x8*)(wtr + (size_t)((tap + 1) * 64 + bu1) * 64 + bc1);
    }
    const int ky = tap / 3, kx = tap - ky * 3;
    #pragma unroll
    for (int ks = 0; ks < 2; ks++) {
      bf16x8 Bf[4];
      #pragma unroll
      for (int nf = 0; nf < 4; nf++) {
        int u = nf * 16 + lrow;
        int byte = BOFF + ((u * 128 + ks * 64 + kg * 16) ^ ((u & 7) << 4));
        Bf[nf] = *(const bf16x8*)(smem + byte);
      }
      #pragma unroll
      for (int mf = 0; mf < 4; mf++) {
        int hpix = (pyv[mf] + ky) * 18 + pxv[mf] + kx;
        int byte = (hpix * 128 + ks * 64 + kg * 16) ^ ((hpix & 7) << 4);
        bf16x8 Af = *(const bf16x8*)(smem + byte);
        #pragma unroll
        for (int nf = 0; nf < 4; nf++)
          acc[mf][nf] = __builtin_amdgcn_mfma_f32_16x16x32_bf16(Af, Bf[nf], acc[mf][nf], 0, 0, 0);
      }
    }
    __syncthreads();
    if (tap < 8) {
      *(u16x8*)(smem + bdst0) = n0;
      *(u16x8*)(smem + bdst1) = n1;
      __syncthreads();
    }
  }

  float bv[4];
  #pragma unroll
  for (int nf = 0; nf < 4; nf++) bv[nf] = bias[nf * 16 + lrow];

  const size_t obase = (size_t)img * H * W;
  #pragma unroll
  for (int mf = 0; mf < 4; mf++) {
    #pragma unroll
    for (int j = 0; j < 4; j++) {
      int p = wv * 64 + mf * 16 + kg * 4 + j;
      int oy = ty + (p >> 4), ox = tx + (p & 15);
      u16* op = out + (obase + (size_t)oy * W + ox) * 64 + lrow;
      #pragma unroll
      for (int nf = 0; nf < 4; nf++)
        op[nf * 16] = f2bf(fmaxf(acc[mf][nf][j] + bv[nf], 0.0f));
    }
  }
}

template<int S1, int S2>
__global__ __launch_bounds__(256) void conv_dual(
    const void* in1, const u16* w1, const float* b1, u16* o1, int H1, int W1, int split,
    const void* in2, const u16* w2, const float* b2, u16* o2, int H2, int W2)
{
  extern __shared__ float4 smem_f4[];
  char* smem = (char*)smem_f4;
  if ((int)blockIdx.x < split)
    conv_body<S1>(smem, in1, w1, b1, o1, H1, W1, blockIdx.x);
  else
    conv_body<S2>(smem, in2, w2, b2, o2, H2, W2, blockIdx.x - split);
}

// ---------------------------------------------------------------------------
// conv 3x3 SAME, 64->1, bias+relu. Tiled: 16x16 px/block, thread=pixel.
// ---------------------------------------------------------------------------
__device__ __forceinline__ void conv3_body(
    char* smem, const u16* __restrict__ in, const float* __restrict__ W3,
    const float* __restrict__ b3, float* __restrict__ out, int H, int W, int bid)
{
  float* wlds = (float*)(smem + 41472);
  const int tilesX = W >> 4;
  const int tilesPerImg = (H >> 4) * tilesX;
  const int img = bid / tilesPerImg;
  const int tile = bid - img * tilesPerImg;
  const int ty = (tile / tilesX) << 4;
  const int tx = (tile % tilesX) << 4;
  const int tid = threadIdx.x;

  for (int idx = tid; idx < 2592; idx += 256) {
    int hpix = idx >> 3;
    int c0 = (idx & 7) << 3;
    int hy = hpix / 18, hx = hpix - hy * 18;
    int gy = ty + hy - 1, gx = tx + hx - 1;
    u16x8 v = {0, 0, 0, 0, 0, 0, 0, 0};
    if (gy >= 0 && gy < H && gx >= 0 && gx < W)
      v = *(const u16x8*)(in + ((size_t)img * H * W + (size_t)gy * W + gx) * 64 + c0);
    int byte = (hpix * 128 + c0 * 2) ^ ((hpix & 7) << 4);
    *(u16x8*)(smem + byte) = v;
  }
  for (int idx = tid; idx < 576; idx += 256) wlds[idx] = W3[idx];
  __syncthreads();

  const int py = tid >> 4, px = tid & 15;
  float acc = 0.0f;
  #pragma unroll
  for (int ky = 0; ky < 3; ky++) {
    #pragma unroll
    for (int kx = 0; kx < 3; kx++) {
      const int hpix = (py + ky) * 18 + (px + kx);
      const float* wp = wlds + (ky * 3 + kx) * 64;
      #pragma unroll
      for (int cg = 0; cg < 8; cg++) {
        int byte = (hpix * 128 + cg * 16) ^ ((hpix & 7) << 4);
        u16x8 v = *(const u16x8*)(smem + byte);
        #pragma unroll
        for (int j = 0; j < 8; j++)
          acc = fmaf(bf2f(v[j]), wp[cg * 8 + j], acc);
      }
    }
  }
  out[(size_t)img * H * W + (size_t)(ty + py) * W + (tx + px)] =
      fmaxf(acc + b3[0], 0.0f);
}

__global__ __launch_bounds__(256) void conv3_dual(
    const u16* in1, const float* W31, const float* b31, float* o1, int H1, int W1, int split,
    const u16* in2, const float* W32, const float* b32, float* o2, int H2, int W2)
{
  extern __shared__ float4 smem_f4[];
  char* smem = (char*)smem_f4;
  if ((int)blockIdx.x < split)
    conv3_body(smem, in1, W31, b31, o1, H1, W1, blockIdx.x);
  else
    conv3_body(smem, in2, W32, b32, o2, H2, W2, blockIdx.x - split);
}

// ---------------------------------------------------------------------------
// fused final: wave per pixel, lane = channel.
// Params computed IN-WAVE: lanes 0-7 each handle one instance's bbox/iw/mask
// math in parallel, then __shfl-broadcast. Removes the precompute dispatch
// and the 8.4MB pp round-trip. Gathers from bf16 pf/bgp.
// ---------------------------------------------------------------------------
__global__ __launch_bounds__(256) void final_blend(
    const u16* __restrict__ pf, const u16* __restrict__ bgp,
    const float* __restrict__ bbox, const float* __restrict__ mask,
    const float* __restrict__ iw, const float* __restrict__ bgw,
    float* __restrict__ out)
{
  const int lane = threadIdx.x & 63;
  const int gpix = blockIdx.x * 4 + (threadIdx.x >> 6);  // grid = 16384 blocks
  const int b = gpix >> 14;
  const int p = gpix & 16383;
  const int Y = p >> 7, X = p & 127;

  // mask coords (pixel-uniform)
  float msy = ((float)Y + 0.5f) * 0.4375f - 0.5f;
  msy = fminf(fmaxf(msy, 0.0f), 55.0f);
  int my0 = (int)floorf(msy); int my1 = min(my0 + 1, 55); float fmy = msy - (float)my0;
  float msx = ((float)X + 0.5f) * 0.4375f - 0.5f;
  msx = fminf(fmaxf(msx, 0.0f), 55.0f);
  int mx0 = (int)floorf(msx); int mx1 = min(mx0 + 1, 55); float fmx = msx - (float)mx0;

  const float ewbg = expf(bgw[gpix]);

  // lanes 0-7: per-instance params (identical arithmetic to reference)
  float ew = 0.0f, wi = 0.0f, fyv = 0.0f, fxv = 0.0f;
  int yxi = 0;
  if (lane < 8) {
    const int i = lane;
    float by1 = bbox[(b * 4 + 0) * 8 + i];
    float by2 = bbox[(b * 4 + 1) * 8 + i];
    float bx1 = bbox[(b * 4 + 2) * 8 + i];
    float bx2 = bbox[(b * 4 + 3) * 8 + i];
    int ysz = max((int)(128.0f * (by2 - by1)), 1);
    int xsz = max((int)(128.0f * (bx2 - bx1)), 1);
    int yfr = (int)(128.0f * by1);
    int xfr = (int)(128.0f * bx1);
    int ly = Y - yfr, lx = X - xfr;
    bool valid = (ly >= 0) && (ly < ysz) && (lx >= 0) && (lx < xsz);
    float rwv = 0.0f;
    int y0 = 0, y1i = 0, x0 = 0, x1i = 0;
    float fy = 0.0f, fx = 0.0f;
    if (valid) {
      float sy = ((float)ly + 0.5f) * (64.0f / (float)ysz) - 0.5f;
      sy = fminf(fmaxf(sy, 0.0f), 63.0f);
      y0 = (int)floorf(sy); y1i = min(y0 + 1, 63); fy = sy - (float)y0;
      float sx = ((float)lx + 0.5f) * (64.0f / (float)xsz) - 0.5f;
      sx = fminf(fmaxf(sx, 0.0f), 63.0f);
      x0 = (int)floorf(sx); x1i = min(x0 + 1, 63); fx = sx - (float)x0;
      const float* iwp = iw + ((size_t)(b * 8 + i)) * 4096;
      float v00 = iwp[y0 * 64 + x0],  v01 = iwp[y0 * 64 + x1i];
      float v10 = iwp[y1i * 64 + x0], v11 = iwp[y1i * 64 + x1i];
      rwv = v00 * (1.f - fy) * (1.f - fx) + v01 * (1.f - fy) * fx
          + v10 * fy * (1.f - fx)         + v11 * fy * fx;
    }
    const float* mp = mask + (size_t)b * 56 * 56 * 8 + i;
    float m00 = mp[(my0 * 56 + mx0) * 8], m01 = mp[(my0 * 56 + mx1) * 8];
    float m10 = mp[(my1 * 56 + mx0) * 8], m11 = mp[(my1 * 56 + mx1) * 8];
    float rm = m00 * (1.f - fmy) * (1.f - fmx) + m01 * (1.f - fmy) * fmx
             + m10 * fmy * (1.f - fmx)         + m11 * fmy * fmx;
    ew = expf(rwv) * rm;
    wi = valid ? ew : 0.0f;
    fyv = fy; fxv = fx;
    yxi = (int)((u32)y0 | ((u32)x0 << 8) | ((u32)y1i << 16) | ((u32)x1i << 24));
  }

  // denom via shfl broadcast (all lanes execute)
  float denom = ewbg;
  #pragma unroll
  for (int i = 0; i < 8; i++) denom += __shfl(ew, i, 64);
  const float invd = 1.0f / denom;

  float accv = (ewbg * invd) * bf2f(bgp[(size_t)gpix * 64 + lane]);
  const u16* pfb = pf + (size_t)b * 2097152;  // 8 * 262144
  #pragma unroll
  for (int i = 0; i < 8; i++) {
    float w = __shfl(wi, i, 64) * invd;   // wave-uniform
    if (w != 0.0f) {                       // execz skip
      float qy = __shfl(fyv, i, 64);
      float qz = __shfl(fxv, i, 64);
      u32 yx = (u32)__shfl(yxi, i, 64);
      int y0 = yx & 255, x0 = (yx >> 8) & 255;
      int y1i = (yx >> 16) & 255, x1i = (yx >> 24) & 255;
      const u16* fp = pfb + (size_t)i * 262144;
      float g00 = bf2f(fp[((size_t)(y0 * 64 + x0)) * 64 + lane]);
      float g01 = bf2f(fp[((size_t)(y0 * 64 + x1i)) * 64 + lane]);
      float g10 = bf2f(fp[((size_t)(y1i * 64 + x0)) * 64 + lane]);
      float g11 = bf2f(fp[((size_t)(y1i * 64 + x1i)) * 64 + lane]);
      float s = g00 * (1.f - qy) * (1.f - qz) + g01 * (1.f - qy) * qz
              + g10 * qy * (1.f - qz)         + g11 * qy * qz;
      accv = fmaf(w, s, accv);
    }
  }
  out[(size_t)gpix * 64 + lane] = accv;
}

// ---------------------------------------------------------------------------
// fallback full final (no packed features). Wave per pixel, lane = c.
// ---------------------------------------------------------------------------
__global__ __launch_bounds__(256) void final_kernel_fb(
    const float* __restrict__ inst, const float* __restrict__ bgf,
    const float* __restrict__ bbox, const float* __restrict__ mask,
    const float* __restrict__ iw, const float* __restrict__ bgw,
    float* __restrict__ out)
{
  const int lane = threadIdx.x & 63;
  const int wvid = blockIdx.x * 4 + (threadIdx.x >> 6);
  const int nw = gridDim.x * 4;
  for (int pix = wvid; pix < 4 * 128 * 128; pix += nw) {
    const int b = pix >> 14;
    const int p = pix & 16383;
    const int Y = p >> 7, X = p & 127;

    float msy = ((float)Y + 0.5f) * 0.4375f - 0.5f;
    msy = fminf(fmaxf(msy, 0.0f), 55.0f);
    int my0 = (int)floorf(msy); int my1 = min(my0 + 1, 55); float fmy = msy - (float)my0;
    float msx = ((float)X + 0.5f) * 0.4375f - 0.5f;
    msx = fminf(fmaxf(msx, 0.0f), 55.0f);
    int mx0 = (int)floorf(msx); int mx1 = min(mx0 + 1, 55); float fmx = msx - (float)mx0;

    const float ewbg = expf(bgw[(size_t)b * 16384 + p]);
    float denom = ewbg;
    float acc = 0.0f;

    for (int i = 0; i < 8; i++) {
      float by1 = bbox[(b * 4 + 0) * 8 + i];
      float by2 = bbox[(b * 4 + 1) * 8 + i];
      float bx1 = bbox[(b * 4 + 2) * 8 + i];
      float bx2 = bbox[(b * 4 + 3) * 8 + i];
      int ysz = max((int)(128.0f * (by2 - by1)), 1);
      int xsz = max((int)(128.0f * (bx2 - bx1)), 1);
      int yfr = (int)(128.0f * by1);
      int xfr = (int)(128.0f * bx1);
      int ly = Y - yfr, lx = X - xfr;
      bool valid = (ly >= 0) && (ly < ysz) && (lx >= 0) && (lx < xsz);
      float rwv = 0.0f;
      int y0 = 0, y1i = 0, x0 = 0, x1i = 0;
      float fy = 0.0f, fx = 0.0f;
      if (valid) {
        float sy = ((float)ly + 0.5f) * (64.0f / (float)ysz) - 0.5f;
        sy = fminf(fmaxf(sy, 0.0f), 63.0f);
        y0 = (int)floorf(sy); y1i = min(y0 + 1, 63); fy = sy - (float)y0;
        float sx = ((float)lx + 0.5f) * (64.0f / (float)xsz) - 0.5f;
        sx = fminf(fmaxf(sx, 0.0f), 63.0f);
        x0 = (int)floorf(sx); x1i = min(x0 + 1, 63); fx = sx - (float)x0;
        const float* iwp = iw + ((size_t)(b * 8 + i)) * 4096;
        float v00 = iwp[y0 * 64 + x0],  v01 = iwp[y0 * 64 + x1i];
        float v10 = iwp[y1i * 64 + x0], v11 = iwp[y1i * 64 + x1i];
        rwv = v00 * (1.f - fy) * (1.f - fx) + v01 * (1.f - fy) * fx
            + v10 * fy * (1.f - fx)         + v11 * fy * fx;
      }
      const float* mp = mask + (size_t)b * 56 * 56 * 8 + i;
      float m00 = mp[(my0 * 56 + mx0) * 8], m01 = mp[(my0 * 56 + mx1) * 8];
      float m10 = mp[(my1 * 56 + mx0) * 8], m11 = mp[(my1 * 56 + mx1) * 8];
      float rm = m00 * (1.f - fmy) * (1.f - fmx) + m01 * (1.f - fmy) * fmx
               + m10 * fmy * (1.f - fmx)         + m11 * fmy * fmx;
      float ew = expf(rwv) * rm;
      denom += ew;
      if (valid) {
        const float* fp = inst + (size_t)b * 2097152 + i;
        float g00 = fp[(((size_t)y0 * 64 + x0) * 64 + lane) * 8];
        float g01 = fp[(((size_t)y0 * 64 + x1i) * 64 + lane) * 8];
        float g10 = fp[(((size_t)y1i * 64 + x0) * 64 + lane) * 8];
        float g11 = fp[(((size_t)y1i * 64 + x1i) * 64 + lane) * 8];
        float s = g00 * (1.f - fy) * (1.f - fx) + g01 * (1.f - fy) * fx
                + g10 * fy * (1.f - fx)         + g11 * fy * fx;
        acc += ew * s;
      }
    }
    const float bgv = bgf[((size_t)b * 16384 + p) * 64 + lane];
    out[((size_t)b * 16384 + p) * 64 + lane] = (ewbg * bgv + acc) / denom;
  }
}

// ---------------------------------------------------------------------------
extern "C" void kernel_launch(void* const* d_in, const int* in_sizes, int n_in,
                              void* d_out, int out_size, void* d_ws, size_t ws_size,
                              hipStream_t stream) {
  const float* inst = (const float*)d_in[0];
  const float* bgf  = (const float*)d_in[1];
  const float* bbox = (const float*)d_in[2];
  const float* mask = (const float*)d_in[3];
  const float* iW1 = (const float*)d_in[4];  const float* ib1 = (const float*)d_in[5];
  const float* iW2 = (const float*)d_in[6];  const float* ib2 = (const float*)d_in[7];
  const float* iW3 = (const float*)d_in[8];  const float* ib3 = (const float*)d_in[9];
  const float* bW1 = (const float*)d_in[10]; const float* bb1 = (const float*)d_in[11];
  const float* bW2 = (const float*)d_in[12]; const float* bb2 = (const float*)d_in[13];
  const float* bW3 = (const float*)d_in[14]; const float* bb3 = (const float*)d_in[15];

  char* ws = (char*)d_ws;
  u16*   wtr  = (u16*)ws;                         // 294,912 B
  u16*   AbI  = (u16*)(ws + 294912);              // 16,777,216 B (inst L1 out)
  u16*   AbB  = (u16*)(ws + 17072128);            //  8,388,608 B (bg L1 out)
  u16*   BbI  = (u16*)(ws + 25460736);            // 16,777,216 B (inst L2 out)
  u16*   BbB  = (u16*)(ws + 42237952);            //  8,388,608 B (bg L2 out)
  float* iw   = (float*)(ws + 50626560);          //    524,288 B
  float* bgw  = (float*)(ws + 51150848);          //    262,144 B
  u16*   pf   = (u16*)(ws + 51412992);            // 16,777,216 B (bf16 packed feats)
  u16*   bgp  = (u16*)(ws + 68190208);            //  8,388,608 B (bf16 bg, dedicated)
  const bool usePf = ws_size >= (size_t)76578816;
  float* outp = (float*)d_out;

  if (usePf) {
    // 4096 transpose + 576 wtrans + 2048 bg-convert
    prep_kernel<<<6720, 256, 0, stream>>>(inst, pf, iW1, iW2, bW1, bW2, wtr,
                                          bgf, bgp, 4096);
    conv_dual<1, 1><<<768, 256, 49664, stream>>>(
        pf,  wtr,             ib1, AbI, 64, 64, 512,
        bgp, wtr + 2 * 36864, bb1, AbB, 128, 128);
    conv_dual<1, 1><<<768, 256, 49664, stream>>>(
        AbI, wtr + 36864,     ib2, BbI, 64, 64, 512,
        AbB, wtr + 3 * 36864, bb2, BbB, 128, 128);
    conv3_dual<<<768, 256, 43776, stream>>>(
        BbI, iW3, ib3, iw, 64, 64, 512,
        BbB, bW3, bb3, bgw, 128, 128);
    final_blend<<<16384, 256, 0, stream>>>(pf, bgp, bbox, mask, iw, bgw, outp);
  } else {
    prep_kernel<<<576, 256, 0, stream>>>(inst, pf, iW1, iW2, bW1, bW2, wtr,
                                         bgf, bgp, 0);   // wtrans only
    conv_dual<2, 0><<<768, 256, 49664, stream>>>(
        inst, wtr,            ib1, AbI, 64, 64, 512,
        bgf, wtr + 2 * 36864, bb1, AbB, 128, 128);
    conv_dual<1, 1><<<768, 256, 49664, stream>>>(
        AbI, wtr + 36864,     ib2, BbI, 64, 64, 512,
        AbB, wtr + 3 * 36864, bb2, BbB, 128, 128);
    conv3_dual<<<768, 256, 43776, stream>>>(
        BbI, iW3, ib3, iw, 64, 64, 512,
        BbB, bW3, bb3, bgw, 128, 128);
    final_kernel_fb<<<2048, 256, 0, stream>>>(inst, bgf, bbox, mask, iw, bgw, outp);
  }
}

// Round 13
// 113.028 us; speedup vs baseline: 1.3763x; 1.0025x over previous
//
#include <hip/hip_runtime.h>
#include <cstdint>

typedef short bf16x8 __attribute__((ext_vector_type(8)));
typedef float f32x4 __attribute__((ext_vector_type(4)));
typedef unsigned short u16;
typedef unsigned short u16x8 __attribute__((ext_vector_type(8)));
typedef unsigned int u32;

__device__ inline u16 f2bf(float f) {
  union { float f; unsigned u; } x; x.f = f;
  unsigned u = x.u + 0x7fffu + ((x.u >> 16) & 1u);
  return (u16)(u >> 16);
}
__device__ inline float bf2f(u16 h) {
  union { unsigned u; float f; } x; x.u = ((unsigned)h) << 16;
  return x.f;
}

// ---------------------------------------------------------------------------
// prep: blocks [0,nT): transpose instance_feature -> pf[(b*8+i)][pix][c] bf16
//       blocks [nT, nT+576): weight transpose wtr[s][tap][u][c] bf16
//       blocks [nT+576, ...): bgf fp32 -> bgp bf16 packed
// ---------------------------------------------------------------------------
__global__ __launch_bounds__(256) void prep_kernel(
    const float* __restrict__ inst, u16* __restrict__ pf,
    const float* __restrict__ w0, const float* __restrict__ w1,
    const float* __restrict__ w2, const float* __restrict__ w3,
    u16* __restrict__ wtr,
    const float* __restrict__ bgf, u16* __restrict__ bgp, int nT)
{
  if ((int)blockIdx.x < nT) {
    const int lane = threadIdx.x & 63;
    const int wvid = blockIdx.x * 4 + (threadIdx.x >> 6);  // 0..16383
    const int b = wvid >> 12;
    const int pix = wvid & 4095;
    const float* s = inst + ((size_t)(b * 4096 + pix)) * 512 + lane * 8;
    float4 v0 = *(const float4*)s;
    float4 v1 = *(const float4*)(s + 4);
    float vals[8] = {v0.x, v0.y, v0.z, v0.w, v1.x, v1.y, v1.z, v1.w};
    #pragma unroll
    for (int i = 0; i < 8; i++)
      pf[(((size_t)(b * 8 + i)) * 4096 + pix) * 64 + lane] = f2bf(vals[i]);
  } else if ((int)blockIdx.x < nT + 576) {
    int id = (blockIdx.x - nT) * 256 + threadIdx.x;
    if (id >= 147456) return;
    int s = id / 36864;
    int r = id - s * 36864;
    int tap = r >> 12;
    int rc = r & 4095;
    int c = rc >> 6, u = rc & 63;
    const float* Ws = (s == 0) ? w0 : (s == 1) ? w1 : (s == 2) ? w2 : w3;
    wtr[(size_t)s * 36864 + ((size_t)tap * 64 + u) * 64 + c] =
        f2bf(Ws[((size_t)tap * 64 + c) * 64 + u]);
  } else {
    size_t id = (size_t)(blockIdx.x - nT - 576) * 256 + threadIdx.x;
    const float* s = bgf + id * 8;
    float4 v0 = *(const float4*)s;
    float4 v1 = *(const float4*)(s + 4);
    u16x8 o;
    o[0] = f2bf(v0.x); o[1] = f2bf(v0.y); o[2] = f2bf(v0.z); o[3] = f2bf(v0.w);
    o[4] = f2bf(v1.x); o[5] = f2bf(v1.y); o[6] = f2bf(v1.z); o[7] = f2bf(v1.w);
    *(u16x8*)(bgp + id * 8) = o;
  }
}

// ---------------------------------------------------------------------------
// conv 3x3 SAME, 64->64, bias+relu, bf16 MFMA implicit GEMM.
// 16x16 tile, 4 waves (proven geometry). B ping-pong across 2x8KB LDS
// buffers -> ONE barrier per tap (9 total vs 17). LDS 57,856 B, 2 blocks/CU.
// SRC: 0 = fp32 packed [img][pix][64], 1 = bf16 packed, 2 = fp32 native inst.
// ---------------------------------------------------------------------------
#define BOFF 41472
template<int SRC>
__device__ __forceinline__ void conv_body(
    char* smem, const void* __restrict__ inv, const u16* __restrict__ wtr,
    const float* __restrict__ bias, u16* __restrict__ out,
    int H, int W, int bid)
{
  const int tilesX = W >> 4;
  const int tilesPerImg = (H >> 4) * tilesX;
  const int img = bid / tilesPerImg;
  const int tile = bid - img * tilesPerImg;
  const int ty = (tile / tilesX) << 4;
  const int tx = (tile % tilesX) << 4;
  const int tid = threadIdx.x;

  for (int idx = tid; idx < 2592; idx += 256) {
    int hpix = idx >> 3;
    int c0 = (idx & 7) << 3;
    int hy = hpix / 18, hx = hpix - hy * 18;
    int gy = ty + hy - 1, gx = tx + hx - 1;
    u16x8 v = {0, 0, 0, 0, 0, 0, 0, 0};
    if (gy >= 0 && gy < H && gx >= 0 && gx < W) {
      if (SRC == 0) {
        const float* s = (const float*)inv + ((size_t)img * H * W + (size_t)gy * W + gx) * 64 + c0;
        #pragma unroll
        for (int j = 0; j < 8; j++) v[j] = f2bf(s[j]);
      } else if (SRC == 1) {
        const u16* s = (const u16*)inv + ((size_t)img * H * W + (size_t)gy * W + gx) * 64 + c0;
        v = *(const u16x8*)s;
      } else {
        int bb = img >> 3, ii = img & 7;
        const float* s = (const float*)inv + ((((size_t)bb * 64 + gy) * 64 + gx) * 64 + c0) * 8 + ii;
        #pragma unroll
        for (int j = 0; j < 8; j++) v[j] = f2bf(s[j * 8]);
      }
    }
    int byte = (hpix * 128 + c0 * 2) ^ ((hpix & 7) << 4);
    *(u16x8*)(smem + byte) = v;
  }

  const int lane = tid & 63;
  const int wv = tid >> 6;
  const int lrow = lane & 15;
  const int kg = lane >> 4;

  // B chunk ids (2 x 16B per tap per thread); relative swizzled offsets
  const int ch0 = tid, ch1 = tid + 256;
  const int bu0 = ch0 >> 3, bc0 = (ch0 & 7) << 3;
  const int bu1 = ch1 >> 3, bc1 = (ch1 & 7) << 3;
  const int brel0 = (bu0 * 128 + bc0 * 2) ^ ((bu0 & 7) << 4);
  const int brel1 = (bu1 * 128 + bc1 * 2) ^ ((bu1 & 7) << 4);

  // stage B tap 0 -> buffer 0
  {
    u16x8 n0 = *(const u16x8*)(wtr + (size_t)bu0 * 64 + bc0);
    u16x8 n1 = *(const u16x8*)(wtr + (size_t)bu1 * 64 + bc1);
    *(u16x8*)(smem + BOFF + brel0) = n0;
    *(u16x8*)(smem + BOFF + brel1) = n1;
  }
  __syncthreads();

  int pyv[4], pxv[4];
  #pragma unroll
  for (int mf = 0; mf < 4; mf++) {
    int p = wv * 64 + mf * 16 + lrow;
    pyv[mf] = p >> 4; pxv[mf] = p & 15;
  }

  f32x4 acc[4][4];
  #pragma unroll
  for (int a = 0; a < 4; a++)
    #pragma unroll
    for (int b = 0; b < 4; b++) { f32x4 z = {0.f, 0.f, 0.f, 0.f}; acc[a][b] = z; }

  for (int tap = 0; tap < 9; tap++) {
    u16x8 n0, n1;
    if (tap < 8) {  // register-prefetch next tap's B (hides under MFMA)
      n0 = *(const u16x8*)(wtr + (size_t)((tap + 1) * 64 + bu0) * 64 + bc0);
      n1 = *(const u16x8*)(wtr + (size_t)((tap + 1) * 64 + bu1) * 64 + bc1);
    }
    const int ky = tap / 3, kx = tap - ky * 3;
    const int bbase = BOFF + ((tap & 1) << 13);
    #pragma unroll
    for (int ks = 0; ks < 2; ks++) {
      bf16x8 Bf[4];
      #pragma unroll
      for (int nf = 0; nf < 4; nf++) {
        int u = nf * 16 + lrow;
        int byte = bbase + ((u * 128 + ks * 64 + kg * 16) ^ ((u & 7) << 4));
        Bf[nf] = *(const bf16x8*)(smem + byte);
      }
      #pragma unroll
      for (int mf = 0; mf < 4; mf++) {
        int hpix = (pyv[mf] + ky) * 18 + pxv[mf] + kx;
        int byte = (hpix * 128 + ks * 64 + kg * 16) ^ ((hpix & 7) << 4);
        bf16x8 Af = *(const bf16x8*)(smem + byte);
        #pragma unroll
        for (int nf = 0; nf < 4; nf++)
          acc[mf][nf] = __builtin_amdgcn_mfma_f32_16x16x32_bf16(Af, Bf[nf], acc[mf][nf], 0, 0, 0);
      }
    }
    if (tap < 8) {  // write NEXT B into the OTHER buffer: one barrier per tap
      const int nb = BOFF + (((tap + 1) & 1) << 13);
      *(u16x8*)(smem + nb + brel0) = n0;
      *(u16x8*)(smem + nb + brel1) = n1;
      __syncthreads();
    }
  }

  float bv[4];
  #pragma unroll
  for (int nf = 0; nf < 4; nf++) bv[nf] = bias[nf * 16 + lrow];

  const size_t obase = (size_t)img * H * W;
  #pragma unroll
  for (int mf = 0; mf < 4; mf++) {
    #pragma unroll
    for (int j = 0; j < 4; j++) {
      int p = wv * 64 + mf * 16 + kg * 4 + j;
      int oy = ty + (p >> 4), ox = tx + (p & 15);
      u16* op = out + (obase + (size_t)oy * W + ox) * 64 + lrow;
      #pragma unroll
      for (int nf = 0; nf < 4; nf++)
        op[nf * 16] = f2bf(fmaxf(acc[mf][nf][j] + bv[nf], 0.0f));
    }
  }
}

template<int S1, int S2>
__global__ __launch_bounds__(256) void conv_dual(
    const void* in1, const u16* w1, const float* b1, u16* o1, int H1, int W1, int split,
    const void* in2, const u16* w2, const float* b2, u16* o2, int H2, int W2)
{
  extern __shared__ float4 smem_f4[];
  char* smem = (char*)smem_f4;
  if ((int)blockIdx.x < split)
    conv_body<S1>(smem, in1, w1, b1, o1, H1, W1, blockIdx.x);
  else
    conv_body<S2>(smem, in2, w2, b2, o2, H2, W2, blockIdx.x - split);
}

// ---------------------------------------------------------------------------
// conv 3x3 SAME, 64->1, bias+relu. Tiled: 16x16 px/block, thread=pixel.
// ---------------------------------------------------------------------------
__device__ __forceinline__ void conv3_body(
    char* smem, const u16* __restrict__ in, const float* __restrict__ W3,
    const float* __restrict__ b3, float* __restrict__ out, int H, int W, int bid)
{
  float* wlds = (float*)(smem + 41472);
  const int tilesX = W >> 4;
  const int tilesPerImg = (H >> 4) * tilesX;
  const int img = bid / tilesPerImg;
  const int tile = bid - img * tilesPerImg;
  const int ty = (tile / tilesX) << 4;
  const int tx = (tile % tilesX) << 4;
  const int tid = threadIdx.x;

  for (int idx = tid; idx < 2592; idx += 256) {
    int hpix = idx >> 3;
    int c0 = (idx & 7) << 3;
    int hy = hpix / 18, hx = hpix - hy * 18;
    int gy = ty + hy - 1, gx = tx + hx - 1;
    u16x8 v = {0, 0, 0, 0, 0, 0, 0, 0};
    if (gy >= 0 && gy < H && gx >= 0 && gx < W)
      v = *(const u16x8*)(in + ((size_t)img * H * W + (size_t)gy * W + gx) * 64 + c0);
    int byte = (hpix * 128 + c0 * 2) ^ ((hpix & 7) << 4);
    *(u16x8*)(smem + byte) = v;
  }
  for (int idx = tid; idx < 576; idx += 256) wlds[idx] = W3[idx];
  __syncthreads();

  const int py = tid >> 4, px = tid & 15;
  float acc = 0.0f;
  #pragma unroll
  for (int ky = 0; ky < 3; ky++) {
    #pragma unroll
    for (int kx = 0; kx < 3; kx++) {
      const int hpix = (py + ky) * 18 + (px + kx);
      const float* wp = wlds + (ky * 3 + kx) * 64;
      #pragma unroll
      for (int cg = 0; cg < 8; cg++) {
        int byte = (hpix * 128 + cg * 16) ^ ((hpix & 7) << 4);
        u16x8 v = *(const u16x8*)(smem + byte);
        #pragma unroll
        for (int j = 0; j < 8; j++)
          acc = fmaf(bf2f(v[j]), wp[cg * 8 + j], acc);
      }
    }
  }
  out[(size_t)img * H * W + (size_t)(ty + py) * W + (tx + px)] =
      fmaxf(acc + b3[0], 0.0f);
}

__global__ __launch_bounds__(256) void conv3_dual(
    const u16* in1, const float* W31, const float* b31, float* o1, int H1, int W1, int split,
    const u16* in2, const float* W32, const float* b32, float* o2, int H2, int W2)
{
  extern __shared__ float4 smem_f4[];
  char* smem = (char*)smem_f4;
  if ((int)blockIdx.x < split)
    conv3_body(smem, in1, W31, b31, o1, H1, W1, blockIdx.x);
  else
    conv3_body(smem, in2, W32, b32, o2, H2, W2, blockIdx.x - split);
}

// ---------------------------------------------------------------------------
// fused final: wave per pixel, lane = channel.
// Params computed IN-WAVE: lanes 0-7 each handle one instance's bbox/iw/mask
// math in parallel, then __shfl-broadcast. Gathers from bf16 pf/bgp.
// ---------------------------------------------------------------------------
__global__ __launch_bounds__(256) void final_blend(
    const u16* __restrict__ pf, const u16* __restrict__ bgp,
    const float* __restrict__ bbox, const float* __restrict__ mask,
    const float* __restrict__ iw, const float* __restrict__ bgw,
    float* __restrict__ out)
{
  const int lane = threadIdx.x & 63;
  const int gpix = blockIdx.x * 4 + (threadIdx.x >> 6);  // grid = 16384 blocks
  const int b = gpix >> 14;
  const int p = gpix & 16383;
  const int Y = p >> 7, X = p & 127;

  float msy = ((float)Y + 0.5f) * 0.4375f - 0.5f;
  msy = fminf(fmaxf(msy, 0.0f), 55.0f);
  int my0 = (int)floorf(msy); int my1 = min(my0 + 1, 55); float fmy = msy - (float)my0;
  float msx = ((float)X + 0.5f) * 0.4375f - 0.5f;
  msx = fminf(fmaxf(msx, 0.0f), 55.0f);
  int mx0 = (int)floorf(msx); int mx1 = min(mx0 + 1, 55); float fmx = msx - (float)mx0;

  const float ewbg = expf(bgw[gpix]);

  float ew = 0.0f, wi = 0.0f, fyv = 0.0f, fxv = 0.0f;
  int yxi = 0;
  if (lane < 8) {
    const int i = lane;
    float by1 = bbox[(b * 4 + 0) * 8 + i];
    float by2 = bbox[(b * 4 + 1) * 8 + i];
    float bx1 = bbox[(b * 4 + 2) * 8 + i];
    float bx2 = bbox[(b * 4 + 3) * 8 + i];
    int ysz = max((int)(128.0f * (by2 - by1)), 1);
    int xsz = max((int)(128.0f * (bx2 - bx1)), 1);
    int yfr = (int)(128.0f * by1);
    int xfr = (int)(128.0f * bx1);
    int ly = Y - yfr, lx = X - xfr;
    bool valid = (ly >= 0) && (ly < ysz) && (lx >= 0) && (lx < xsz);
    float rwv = 0.0f;
    int y0 = 0, y1i = 0, x0 = 0, x1i = 0;
    float fy = 0.0f, fx = 0.0f;
    if (valid) {
      float sy = ((float)ly + 0.5f) * (64.0f / (float)ysz) - 0.5f;
      sy = fminf(fmaxf(sy, 0.0f), 63.0f);
      y0 = (int)floorf(sy); y1i = min(y0 + 1, 63); fy = sy - (float)y0;
      float sx = ((float)lx + 0.5f) * (64.0f / (float)xsz) - 0.5f;
      sx = fminf(fmaxf(sx, 0.0f), 63.0f);
      x0 = (int)floorf(sx); x1i = min(x0 + 1, 63); fx = sx - (float)x0;
      const float* iwp = iw + ((size_t)(b * 8 + i)) * 4096;
      float v00 = iwp[y0 * 64 + x0],  v01 = iwp[y0 * 64 + x1i];
      float v10 = iwp[y1i * 64 + x0], v11 = iwp[y1i * 64 + x1i];
      rwv = v00 * (1.f - fy) * (1.f - fx) + v01 * (1.f - fy) * fx
          + v10 * fy * (1.f - fx)         + v11 * fy * fx;
    }
    const float* mp = mask + (size_t)b * 56 * 56 * 8 + i;
    float m00 = mp[(my0 * 56 + mx0) * 8], m01 = mp[(my0 * 56 + mx1) * 8];
    float m10 = mp[(my1 * 56 + mx0) * 8], m11 = mp[(my1 * 56 + mx1) * 8];
    float rm = m00 * (1.f - fmy) * (1.f - fmx) + m01 * (1.f - fmy) * fmx
             + m10 * fmy * (1.f - fmx)         + m11 * fmy * fmx;
    ew = expf(rwv) * rm;
    wi = valid ? ew : 0.0f;
    fyv = fy; fxv = fx;
    yxi = (int)((u32)y0 | ((u32)x0 << 8) | ((u32)y1i << 16) | ((u32)x1i << 24));
  }

  float denom = ewbg;
  #pragma unroll
  for (int i = 0; i < 8; i++) denom += __shfl(ew, i, 64);
  const float invd = 1.0f / denom;

  float accv = (ewbg * invd) * bf2f(bgp[(size_t)gpix * 64 + lane]);
  const u16* pfb = pf + (size_t)b * 2097152;  // 8 * 262144
  #pragma unroll
  for (int i = 0; i < 8; i++) {
    float w = __shfl(wi, i, 64) * invd;   // wave-uniform
    if (w != 0.0f) {                       // execz skip
      float qy = __shfl(fyv, i, 64);
      float qz = __shfl(fxv, i, 64);
      u32 yx = (u32)__shfl(yxi, i, 64);
      int y0 = yx & 255, x0 = (yx >> 8) & 255;
      int y1i = (yx >> 16) & 255, x1i = (yx >> 24) & 255;
      const u16* fp = pfb + (size_t)i * 262144;
      float g00 = bf2f(fp[((size_t)(y0 * 64 + x0)) * 64 + lane]);
      float g01 = bf2f(fp[((size_t)(y0 * 64 + x1i)) * 64 + lane]);
      float g10 = bf2f(fp[((size_t)(y1i * 64 + x0)) * 64 + lane]);
      float g11 = bf2f(fp[((size_t)(y1i * 64 + x1i)) * 64 + lane]);
      float s = g00 * (1.f - qy) * (1.f - qz) + g01 * (1.f - qy) * qz
              + g10 * qy * (1.f - qz)         + g11 * qy * qz;
      accv = fmaf(w, s, accv);
    }
  }
  out[(size_t)gpix * 64 + lane] = accv;
}

// ---------------------------------------------------------------------------
// fallback full final (no packed features). Wave per pixel, lane = c.
// ---------------------------------------------------------------------------
__global__ __launch_bounds__(256) void final_kernel_fb(
    const float* __restrict__ inst, const float* __restrict__ bgf,
    const float* __restrict__ bbox, const float* __restrict__ mask,
    const float* __restrict__ iw, const float* __restrict__ bgw,
    float* __restrict__ out)
{
  const int lane = threadIdx.x & 63;
  const int wvid = blockIdx.x * 4 + (threadIdx.x >> 6);
  const int nw = gridDim.x * 4;
  for (int pix = wvid; pix < 4 * 128 * 128; pix += nw) {
    const int b = pix >> 14;
    const int p = pix & 16383;
    const int Y = p >> 7, X = p & 127;

    float msy = ((float)Y + 0.5f) * 0.4375f - 0.5f;
    msy = fminf(fmaxf(msy, 0.0f), 55.0f);
    int my0 = (int)floorf(msy); int my1 = min(my0 + 1, 55); float fmy = msy - (float)my0;
    float msx = ((float)X + 0.5f) * 0.4375f - 0.5f;
    msx = fminf(fmaxf(msx, 0.0f), 55.0f);
    int mx0 = (int)floorf(msx); int mx1 = min(mx0 + 1, 55); float fmx = msx - (float)mx0;

    const float ewbg = expf(bgw[(size_t)b * 16384 + p]);
    float denom = ewbg;
    float acc = 0.0f;

    for (int i = 0; i < 8; i++) {
      float by1 = bbox[(b * 4 + 0) * 8 + i];
      float by2 = bbox[(b * 4 + 1) * 8 + i];
      float bx1 = bbox[(b * 4 + 2) * 8 + i];
      float bx2 = bbox[(b * 4 + 3) * 8 + i];
      int ysz = max((int)(128.0f * (by2 - by1)), 1);
      int xsz = max((int)(128.0f * (bx2 - bx1)), 1);
      int yfr = (int)(128.0f * by1);
      int xfr = (int)(128.0f * bx1);
      int ly = Y - yfr, lx = X - xfr;
      bool valid = (ly >= 0) && (ly < ysz) && (lx >= 0) && (lx < xsz);
      float rwv = 0.0f;
      int y0 = 0, y1i = 0, x0 = 0, x1i = 0;
      float fy = 0.0f, fx = 0.0f;
      if (valid) {
        float sy = ((float)ly + 0.5f) * (64.0f / (float)ysz) - 0.5f;
        sy = fminf(fmaxf(sy, 0.0f), 63.0f);
        y0 = (int)floorf(sy); y1i = min(y0 + 1, 63); fy = sy - (float)y0;
        float sx = ((float)lx + 0.5f) * (64.0f / (float)xsz) - 0.5f;
        sx = fminf(fmaxf(sx, 0.0f), 63.0f);
        x0 = (int)floorf(sx); x1i = min(x0 + 1, 63); fx = sx - (float)x0;
        const float* iwp = iw + ((size_t)(b * 8 + i)) * 4096;
        float v00 = iwp[y0 * 64 + x0],  v01 = iwp[y0 * 64 + x1i];
        float v10 = iwp[y1i * 64 + x0], v11 = iwp[y1i * 64 + x1i];
        rwv = v00 * (1.f - fy) * (1.f - fx) + v01 * (1.f - fy) * fx
            + v10 * fy * (1.f - fx)         + v11 * fy * fx;
      }
      const float* mp = mask + (size_t)b * 56 * 56 * 8 + i;
      float m00 = mp[(my0 * 56 + mx0) * 8], m01 = mp[(my0 * 56 + mx1) * 8];
      float m10 = mp[(my1 * 56 + mx0) * 8], m11 = mp[(my1 * 56 + mx1) * 8];
      float rm = m00 * (1.f - fmy) * (1.f - fmx) + m01 * (1.f - fmy) * fmx
               + m10 * fmy * (1.f - fmx)         + m11 * fmy * fmx;
      float ew = expf(rwv) * rm;
      denom += ew;
      if (valid) {
        const float* fp = inst + (size_t)b * 2097152 + i;
        float g00 = fp[(((size_t)y0 * 64 + x0) * 64 + lane) * 8];
        float g01 = fp[(((size_t)y0 * 64 + x1i) * 64 + lane) * 8];
        float g10 = fp[(((size_t)y1i * 64 + x0) * 64 + lane) * 8];
        float g11 = fp[(((size_t)y1i * 64 + x1i) * 64 + lane) * 8];
        float s = g00 * (1.f - fy) * (1.f - fx) + g01 * (1.f - fy) * fx
                + g10 * fy * (1.f - fx)         + g11 * fy * fx;
        acc += ew * s;
      }
    }
    const float bgv = bgf[((size_t)b * 16384 + p) * 64 + lane];
    out[((size_t)b * 16384 + p) * 64 + lane] = (ewbg * bgv + acc) / denom;
  }
}

// ---------------------------------------------------------------------------
extern "C" void kernel_launch(void* const* d_in, const int* in_sizes, int n_in,
                              void* d_out, int out_size, void* d_ws, size_t ws_size,
                              hipStream_t stream) {
  const float* inst = (const float*)d_in[0];
  const float* bgf  = (const float*)d_in[1];
  const float* bbox = (const float*)d_in[2];
  const float* mask = (const float*)d_in[3];
  const float* iW1 = (const float*)d_in[4];  const float* ib1 = (const float*)d_in[5];
  const float* iW2 = (const float*)d_in[6];  const float* ib2 = (const float*)d_in[7];
  const float* iW3 = (const float*)d_in[8];  const float* ib3 = (const float*)d_in[9];
  const float* bW1 = (const float*)d_in[10]; const float* bb1 = (const float*)d_in[11];
  const float* bW2 = (const float*)d_in[12]; const float* bb2 = (const float*)d_in[13];
  const float* bW3 = (const float*)d_in[14]; const float* bb3 = (const float*)d_in[15];

  char* ws = (char*)d_ws;
  u16*   wtr  = (u16*)ws;                         // 294,912 B
  u16*   AbI  = (u16*)(ws + 294912);              // 16,777,216 B (inst L1 out)
  u16*   AbB  = (u16*)(ws + 17072128);            //  8,388,608 B (bg L1 out)
  u16*   BbI  = (u16*)(ws + 25460736);            // 16,777,216 B (inst L2 out)
  u16*   BbB  = (u16*)(ws + 42237952);            //  8,388,608 B (bg L2 out)
  float* iw   = (float*)(ws + 50626560);          //    524,288 B
  float* bgw  = (float*)(ws + 51150848);          //    262,144 B
  u16*   pf   = (u16*)(ws + 51412992);            // 16,777,216 B (bf16 packed feats)
  u16*   bgp  = (u16*)(ws + 68190208);            //  8,388,608 B (bf16 bg, dedicated)
  const bool usePf = ws_size >= (size_t)76578816;
  float* outp = (float*)d_out;

  if (usePf) {
    // 4096 transpose + 576 wtrans + 2048 bg-convert
    prep_kernel<<<6720, 256, 0, stream>>>(inst, pf, iW1, iW2, bW1, bW2, wtr,
                                          bgf, bgp, 4096);
    conv_dual<1, 1><<<768, 256, 57856, stream>>>(
        pf,  wtr,             ib1, AbI, 64, 64, 512,
        bgp, wtr + 2 * 36864, bb1, AbB, 128, 128);
    conv_dual<1, 1><<<768, 256, 57856, stream>>>(
        AbI, wtr + 36864,     ib2, BbI, 64, 64, 512,
        AbB, wtr + 3 * 36864, bb2, BbB, 128, 128);
    conv3_dual<<<768, 256, 43776, stream>>>(
        BbI, iW3, ib3, iw, 64, 64, 512,
        BbB, bW3, bb3, bgw, 128, 128);
    final_blend<<<16384, 256, 0, stream>>>(pf, bgp, bbox, mask, iw, bgw, outp);
  } else {
    prep_kernel<<<576, 256, 0, stream>>>(inst, pf, iW1, iW2, bW1, bW2, wtr,
                                         bgf, bgp, 0);   // wtrans only
    conv_dual<2, 0><<<768, 256, 57856, stream>>>(
        inst, wtr,            ib1, AbI, 64, 64, 512,
        bgf, wtr + 2 * 36864, bb1, AbB, 128, 128);
    conv_dual<1, 1><<<768, 256, 57856, stream>>>(
        AbI, wtr + 36864,     ib2, BbI, 64, 64, 512,
        AbB, wtr + 3 * 36864, bb2, BbB, 128, 128);
    conv3_dual<<<768, 256, 43776, stream>>>(
        BbI, iW3, ib3, iw, 64, 64, 512,
        BbB, bW3, bb3, bgw, 128, 128);
    final_kernel_fb<<<2048, 256, 0, stream>>>(inst, bgf, bbox, mask, iw, bgw, outp);
  }
}